// Round 4
// baseline (724.546 us; speedup 1.0000x reference)
//
#include <hip/hip_runtime.h>
#include <stdint.h>

typedef unsigned short u16;
typedef unsigned int u32;
typedef __attribute__((ext_vector_type(8))) short frag_ab;   // 8 bf16
typedef __attribute__((ext_vector_type(4))) float f32x4;

__device__ __forceinline__ u16 f2b(float f) {
  unsigned u = __float_as_uint(f);
  return (u16)((u + 0x7fffu + ((u >> 16) & 1u)) >> 16);
}
__device__ __forceinline__ float b2f(u16 u) {
  return __uint_as_float(((unsigned)u) << 16);
}

// ---------------------------------------------------------------------------

__global__ void k_zero(int* __restrict__ p, int n) {
  int i = blockIdx.x * 256 + threadIdx.x;
  if (i < n) p[i] = 0;
}

__global__ void k_detect(const int* __restrict__ ei, int* __restrict__ flag) {
  int t = threadIdx.x;  // 64 threads
  int v = ei[2 * t + 1];
  unsigned long long b = __ballot(v == 0);
  if (t == 0) *flag = (b == ~0ULL) ? 1 : 0;
}

__device__ __forceinline__ int edge_at(const void* ei, long pos, int is64) {
  if (is64) return (int)((const long long*)ei)[pos];
  return ((const int*)ei)[pos];
}

// per-row degree (for dinv only)
__global__ void k_hist(const void* __restrict__ ei, int E, int* __restrict__ cnt,
                       const int* __restrict__ flag) {
  int e = blockIdx.x * 256 + threadIdx.x;
  int is64 = *flag;
  if (e < E) atomicAdd(&cnt[edge_at(ei, e, is64)], 1);
}

__global__ void k_dinv(const int* __restrict__ cnt, float* __restrict__ dinv, int N) {
  int i = blockIdx.x * 256 + threadIdx.x;
  if (i < N) dinv[i] = rsqrtf((float)cnt[i] + 1.0f);  // +1 = self loop
}

// per-(chunk,bucket) histogram; bucket = row>>9 (RPB=512); NB <= 512
__global__ __launch_bounds__(256) void k_bhist(
    const void* __restrict__ ei, int E, int CH, int NB, int NBpad,
    int* __restrict__ bh, const int* __restrict__ flag) {
  __shared__ int cnt[512];
  const int k = blockIdx.x, tid = threadIdx.x;
  int is64 = *flag;
  for (int t = tid; t < NB; t += 256) cnt[t] = 0;
  __syncthreads();
  int e0 = k * CH, e1 = min(E, e0 + CH);
  for (int e = e0 + tid; e < e1; e += 256)
    atomicAdd(&cnt[edge_at(ei, e, is64) >> 9], 1);
  __syncthreads();
  for (int t = tid; t < NB; t += 256) bh[k * NBpad + t] = cnt[t];
}

// bucket starts + in-place column prefix: bh[k][b] -> absolute offset
__global__ __launch_bounds__(256) void k_cscan(
    int* __restrict__ bh, int* __restrict__ bstart, int NB, int NBpad, int E) {
  __shared__ int s[256];
  const int b = threadIdx.x;
  int tot = 0;
  if (b < NB)
    for (int k = 0; k < 256; ++k) tot += bh[k * NBpad + b];
  s[b] = (b < NB) ? tot : 0;
  __syncthreads();
  for (int off = 1; off < 256; off <<= 1) {
    int u = (b >= off) ? s[b - off] : 0;
    __syncthreads();
    s[b] += u;
    __syncthreads();
  }
  int excl = s[b] - tot;
  if (b < NB) {
    bstart[b] = excl;
    int run = excl;
    for (int k = 0; k < 256; ++k) {
      int t = bh[k * NBpad + b];
      bh[k * NBpad + b] = run;
      run += t;
    }
  }
  if (b == 0) bstart[NB] = E;
}

// append edges to this chunk's reserved per-bucket runs; pack (row&511)<<23|col
__global__ __launch_bounds__(256) void k_partition(
    const void* __restrict__ ei, int E, int CH, int NB, int NBpad,
    const int* __restrict__ bh, u32* __restrict__ staged,
    const int* __restrict__ flag) {
  __shared__ int cur[512];
  const int k = blockIdx.x, tid = threadIdx.x;
  int is64 = *flag;
  for (int t = tid; t < NB; t += 256) cur[t] = bh[k * NBpad + t];
  __syncthreads();
  int e0 = k * CH, e1 = min(E, e0 + CH);
  for (int e = e0 + tid; e < e1; e += 256) {
    int r = edge_at(ei, e, is64);
    int c = edge_at(ei, (long)E + e, is64);
    int pos = atomicAdd(&cur[r >> 9], 1);
    staged[pos] = ((u32)(r & 511) << 23) | (u32)c;
  }
}

// one block per bucket: fp32 accumulator for 512 rows x 64 feats in LDS
__global__ __launch_bounds__(1024) void k_agg_lds(
    const u32* __restrict__ staged, const int* __restrict__ bstart,
    const u16* __restrict__ xb, const float* __restrict__ dinv,
    u16* __restrict__ aggb, int N) {
  __shared__ float acc[512 * 64];   // 128KB
  __shared__ float sdv[512];        // 2KB
  const int b = blockIdx.x, tid = threadIdx.x;
  const int r0 = b << 9;
  for (int i = tid; i < 512 * 64; i += 1024) acc[i] = 0.f;
  for (int i = tid; i < 512; i += 1024)
    sdv[i] = (r0 + i < N) ? dinv[r0 + i] : 0.f;
  __syncthreads();
  const int wv = tid >> 6, f = tid & 63;
  const int j0 = bstart[b], j1 = bstart[b + 1];
  const int nj = j1 - j0;
  const int span = (nj + 15) >> 4;
  int j = j0 + wv * span;
  int je = min(j + span, j1);
  for (; j + 4 <= je; j += 4) {
    u32 v0 = staged[j], v1 = staged[j + 1], v2 = staged[j + 2], v3 = staged[j + 3];
    int c0 = v0 & 0x7FFFFF, c1 = v1 & 0x7FFFFF, c2 = v2 & 0x7FFFFF, c3 = v3 & 0x7FFFFF;
    int rl0 = v0 >> 23, rl1 = v1 >> 23, rl2 = v2 >> 23, rl3 = v3 >> 23;
    float w0 = sdv[rl0] * dinv[c0];
    float w1 = sdv[rl1] * dinv[c1];
    float w2 = sdv[rl2] * dinv[c2];
    float w3 = sdv[rl3] * dinv[c3];
    float x0 = b2f(xb[(long)c0 * 64 + f]);
    float x1 = b2f(xb[(long)c1 * 64 + f]);
    float x2 = b2f(xb[(long)c2 * 64 + f]);
    float x3 = b2f(xb[(long)c3 * 64 + f]);
    atomicAdd(&acc[rl0 * 64 + f], x0 * w0);
    atomicAdd(&acc[rl1 * 64 + f], x1 * w1);
    atomicAdd(&acc[rl2 * 64 + f], x2 * w2);
    atomicAdd(&acc[rl3 * 64 + f], x3 * w3);
  }
  for (; j < je; ++j) {
    u32 v = staged[j];
    int c = v & 0x7FFFFF, rl = v >> 23;
    atomicAdd(&acc[rl * 64 + f], b2f(xb[(long)c * 64 + f]) * sdv[rl] * dinv[c]);
  }
  __syncthreads();
  for (int i = tid; i < 512 * 64; i += 1024) {
    int rl = i >> 6, ff = i & 63;
    int r = r0 + rl;
    if (r < N) {
      float d = sdv[rl];
      float v = acc[i] + b2f(xb[(long)r * 64 + ff]) * d * d;
      aggb[(long)r * 64 + ff] = f2b(v);
    }
  }
}

// fp32 -> bf16, 8 elems/thread
__global__ void k_cvt(const float* __restrict__ src, u16* __restrict__ dst, long n) {
  long i = ((long)blockIdx.x * 256 + threadIdx.x) * 8;
  if (i + 8 <= n) {
    float4 v0 = *(const float4*)(src + i);
    float4 v1 = *(const float4*)(src + i + 4);
    frag_ab o;
    o[0] = (short)f2b(v0.x); o[1] = (short)f2b(v0.y);
    o[2] = (short)f2b(v0.z); o[3] = (short)f2b(v0.w);
    o[4] = (short)f2b(v1.x); o[5] = (short)f2b(v1.y);
    o[6] = (short)f2b(v1.z); o[7] = (short)f2b(v1.w);
    *(frag_ab*)(dst + i) = o;
  }
}

// Wxp = W2x @ Wc_top ; Wap = W2a @ Wc_bot ; bp = b2x@Wc_top + b2a@Wc_bot + bc
__global__ void k_wprod(const float* __restrict__ W2x, const float* __restrict__ W2a,
                        const float* __restrict__ Wc, const float* __restrict__ b2x,
                        const float* __restrict__ b2a, const float* __restrict__ bc,
                        float* __restrict__ Wxp, float* __restrict__ Wap,
                        float* __restrict__ bp) {
  int b = blockIdx.x, t = threadIdx.x;
  if (b < 128) {
    int j = t & 127;
    bool isX = (t < 128);
    const float* wrow = isX ? (W2x + b * 128) : (W2a + b * 128);
    const float* wc = isX ? Wc : (Wc + 128 * 128);
    float s = 0.f;
    for (int m = 0; m < 128; ++m) s = fmaf(wrow[m], wc[m * 128 + j], s);
    (isX ? Wxp : Wap)[b * 128 + j] = s;
  } else if (t < 128) {
    float s = bc[t];
    for (int m = 0; m < 128; ++m)
      s += b2x[m] * Wc[m * 128 + t] + b2a[m] * Wc[(128 + m) * 128 + t];
    bp[t] = s;
  }
}

// pack W[K][Nc] fp32 row-major into bf16 B-fragment-linear order
__global__ void k_pack(const float* __restrict__ W, u16* __restrict__ dst,
                       int K, int Nc) {
  int i = blockIdx.x * 256 + threadIdx.x;
  if (i >= K * Nc) return;
  int b = i & 7, l = (i >> 3) & 63, f = i >> 9;
  int KB = K >> 5;
  int kb = f % KB, nb = f / KB;
  int k = kb * 32 + (l >> 4) * 8 + b;
  int n = nb * 16 + (l & 15);
  dst[i] = f2b(W[k * Nc + n]);
}

// ---------------------------------------------------------------------------
// Fused MLP (unchanged from R3)
// ---------------------------------------------------------------------------
__global__ __launch_bounds__(256) void k_mlp(
    const u16* __restrict__ xb, const u16* __restrict__ aggb,
    const u16* __restrict__ W1xf, const u16* __restrict__ W1af,
    const float* __restrict__ b1x, const float* __restrict__ b1a,
    const u16* __restrict__ Wxpf, const u16* __restrict__ Wapf,
    const float* __restrict__ bp,
    const u16* __restrict__ Wclsf, const float* __restrict__ bcls,
    float* __restrict__ out, int N) {
  __shared__ u16 H1[4][16 * 256];   // 32KB
  __shared__ u16 H2[4][16 * 128];   // 16KB
  const int w = threadIdx.x >> 6;
  const int lane = threadIdx.x & 63;
  const int m0 = blockIdx.x * 64 + w * 16;
  const int lm = lane & 15;
  const int lq = lane >> 4;
  u16* h1 = H1[w];
  u16* h2 = H2[w];

  for (int br = 0; br < 2; ++br) {
    const u16* A = br ? aggb : xb;
    const u16* Wf = br ? W1af : W1xf;
    const float* bias = br ? b1a : b1x;
    const u16* ap = A + (long)(m0 + lm) * 64 + lq * 8;
    frag_ab a0 = *(const frag_ab*)(ap);
    frag_ab a1 = *(const frag_ab*)(ap + 32);
#pragma unroll
    for (int nb = 0; nb < 8; ++nb) {
      frag_ab b0 = *(const frag_ab*)(Wf + (size_t)((nb * 2 + 0) * 64 + lane) * 8);
      frag_ab b1v = *(const frag_ab*)(Wf + (size_t)((nb * 2 + 1) * 64 + lane) * 8);
      f32x4 acc = {0.f, 0.f, 0.f, 0.f};
      acc = __builtin_amdgcn_mfma_f32_16x16x32_bf16(a0, b0, acc, 0, 0, 0);
      acc = __builtin_amdgcn_mfma_f32_16x16x32_bf16(a1, b1v, acc, 0, 0, 0);
      int col = nb * 16 + lm;
      float bv = bias[col];
#pragma unroll
      for (int r = 0; r < 4; ++r) {
        int row = lq * 4 + r;
        h1[(row * 256 + br * 128 + col) ^ ((row & 7) << 3)] =
            f2b(fmaxf(acc[r] + bv, 0.f));
      }
    }
  }
  __syncthreads();

  frag_ab hfr[8];
#pragma unroll
  for (int kb = 0; kb < 8; ++kb)
    hfr[kb] = *(const frag_ab*)&h1[(lm * 256 + kb * 32 + lq * 8) ^ ((lm & 7) << 3)];
#pragma unroll
  for (int nb = 0; nb < 8; ++nb) {
    f32x4 acc = {0.f, 0.f, 0.f, 0.f};
#pragma unroll
    for (int kb = 0; kb < 8; ++kb) {
      const u16* Wf2 = (kb < 4) ? Wxpf : Wapf;
      frag_ab b = *(const frag_ab*)(Wf2 + (size_t)((nb * 4 + (kb & 3)) * 64 + lane) * 8);
      acc = __builtin_amdgcn_mfma_f32_16x16x32_bf16(hfr[kb], b, acc, 0, 0, 0);
    }
    int col = nb * 16 + lm;
    float bv = bp[col];
#pragma unroll
    for (int r = 0; r < 4; ++r) {
      int row = lq * 4 + r;
      h2[(row * 128 + col) ^ ((row & 7) << 3)] = f2b(fmaxf(acc[r] + bv, 0.f));
    }
  }
  __syncthreads();

  frag_ab h3[4];
#pragma unroll
  for (int kb = 0; kb < 4; ++kb)
    h3[kb] = *(const frag_ab*)&h2[(lm * 128 + kb * 32 + lq * 8) ^ ((lm & 7) << 3)];
#pragma unroll
  for (int nb = 0; nb < 4; ++nb) {
    f32x4 acc = {0.f, 0.f, 0.f, 0.f};
#pragma unroll
    for (int kb = 0; kb < 4; ++kb) {
      frag_ab b = *(const frag_ab*)(Wclsf + (size_t)((nb * 4 + kb) * 64 + lane) * 8);
      acc = __builtin_amdgcn_mfma_f32_16x16x32_bf16(h3[kb], b, acc, 0, 0, 0);
    }
    int col = nb * 16 + lm;
    float bv = bcls[col];
#pragma unroll
    for (int r = 0; r < 4; ++r) {
      int grow = m0 + lq * 4 + r;
      if (grow < N) out[(long)grow * 64 + col] = acc[r] + bv;
    }
  }
}

extern "C" void kernel_launch(void* const* d_in, const int* in_sizes, int n_in,
                              void* d_out, int out_size, void* d_ws, size_t ws_size,
                              hipStream_t stream) {
  const float* x    = (const float*)d_in[0];
  const void*  ei   = d_in[1];
  const float* W1x  = (const float*)d_in[2];
  const float* b1x  = (const float*)d_in[3];
  const float* W2x  = (const float*)d_in[4];
  const float* b2x  = (const float*)d_in[5];
  const float* W1a  = (const float*)d_in[6];
  const float* b1a  = (const float*)d_in[7];
  const float* W2a  = (const float*)d_in[8];
  const float* b2a  = (const float*)d_in[9];
  const float* Wc   = (const float*)d_in[10];
  const float* bc   = (const float*)d_in[11];
  const float* Wcls = (const float*)d_in[12];
  const float* bcls = (const float*)d_in[13];
  const int N = in_sizes[0] / 64;   // assumes N <= 131072 (fixed harness N=100000)
  const int E = in_sizes[1] / 2;

  const int NB = (N + 511) >> 9;          // 512 rows per bucket
  const int NBpad = (NB + 63) & ~63;
  const int CH = (E + 255) / 256;

  float* ws = (float*)d_ws;
  long nAlign = (N + 255) & ~255L;
  float* dinv = ws;                                    // N
  int*   cntI = (int*)(ws + nAlign);                   // N
  int*   flag = (int*)(ws + 2 * nAlign);               // 1
  u16*   xb   = (u16*)(ws + 2 * nAlign + 256);         // N*64 bf16
  u16*   aggb = xb + (long)N * 64;                     // N*64 bf16
  float* Wxp  = (float*)(aggb + (long)N * 64);         // 16384
  float* Wap  = Wxp + 16384;                           // 16384
  float* bp   = Wap + 16384;                           // 128
  u16*   W1xf = (u16*)(bp + 128);                      // 8192
  u16*   W1af = W1xf + 8192;                           // 8192
  u16*   Wxpf = W1af + 8192;                           // 16384
  u16*   Wapf = Wxpf + 16384;                          // 16384
  u16*   Wclsf = Wapf + 16384;                         // 8192
  int*   bh   = (int*)(Wclsf + 8192);                  // 256*NBpad
  int*   bstart = bh + 256 * NBpad;                    // NB+1
  u32*   staged = (u32*)(bstart + NB + 64);            // E
  float* out = (float*)d_out;

  const int nb = (N + 255) / 256;
  k_detect<<<1, 64, 0, stream>>>((const int*)ei, flag);
  k_zero<<<nb, 256, 0, stream>>>(cntI, N);
  k_hist<<<(E + 255) / 256, 256, 0, stream>>>(ei, E, cntI, flag);
  k_dinv<<<nb, 256, 0, stream>>>(cntI, dinv, N);
  k_cvt<<<(int)(((long)N * 64 / 8 + 255) / 256), 256, 0, stream>>>(x, xb, (long)N * 64);
  k_bhist<<<256, 256, 0, stream>>>(ei, E, CH, NB, NBpad, bh, flag);
  k_cscan<<<1, 256, 0, stream>>>(bh, bstart, NB, NBpad, E);
  k_partition<<<256, 256, 0, stream>>>(ei, E, CH, NB, NBpad, bh, staged, flag);
  k_agg_lds<<<NB, 1024, 0, stream>>>(staged, bstart, xb, dinv, aggb, N);
  k_wprod<<<129, 256, 0, stream>>>(W2x, W2a, Wc, b2x, b2a, bc, Wxp, Wap, bp);
  k_pack<<<32, 256, 0, stream>>>(W1x, W1xf, 64, 128);
  k_pack<<<32, 256, 0, stream>>>(W1a, W1af, 64, 128);
  k_pack<<<64, 256, 0, stream>>>(Wxp, Wxpf, 128, 128);
  k_pack<<<64, 256, 0, stream>>>(Wap, Wapf, 128, 128);
  k_pack<<<32, 256, 0, stream>>>(Wcls, Wclsf, 128, 64);
  k_mlp<<<(N + 63) / 64, 256, 0, stream>>>(xb, aggb, W1xf, W1af, b1x, b1a,
                                           Wxpf, Wapf, bp, Wclsf, bcls, out, N);
}

// Round 5
// 246.904 us; speedup vs baseline: 2.9345x; 2.9345x over previous
//
#include <hip/hip_runtime.h>
#include <stdint.h>

typedef unsigned short u16;
typedef unsigned int u32;
typedef __attribute__((ext_vector_type(8))) short frag_ab;   // 8 bf16
typedef __attribute__((ext_vector_type(4))) float f32x4;

__device__ __forceinline__ u16 f2b(float f) {
  unsigned u = __float_as_uint(f);
  return (u16)((u + 0x7fffu + ((u >> 16) & 1u)) >> 16);
}
__device__ __forceinline__ float b2f(u16 u) {
  return __uint_as_float(((unsigned)u) << 16);
}

// ---------------------------------------------------------------------------

__global__ void k_zero(int* __restrict__ p, int n) {
  int i = blockIdx.x * 256 + threadIdx.x;
  if (i < n) p[i] = 0;
}

__global__ void k_detect(const int* __restrict__ ei, int* __restrict__ flag) {
  int t = threadIdx.x;  // 64 threads
  int v = ei[2 * t + 1];
  unsigned long long b = __ballot(v == 0);
  if (t == 0) *flag = (b == ~0ULL) ? 1 : 0;
}

__device__ __forceinline__ int edge_at(const void* ei, long pos, int is64) {
  if (is64) return (int)((const long long*)ei)[pos];
  return ((const int*)ei)[pos];
}

// per-row degree
__global__ void k_hist(const void* __restrict__ ei, int E, int* __restrict__ cnt,
                       const int* __restrict__ flag) {
  int e = blockIdx.x * 256 + threadIdx.x;
  int is64 = *flag;
  if (e < E) atomicAdd(&cnt[edge_at(ei, e, is64)], 1);
}

// inclusive scan per 256-block
__global__ void k_scan1(const int* __restrict__ cnt, int* __restrict__ incl,
                        int* __restrict__ bsum, int N) {
  __shared__ int s[256];
  int t = threadIdx.x, i = blockIdx.x * 256 + t;
  int v = (i < N) ? cnt[i] : 0;
  s[t] = v;
  __syncthreads();
  for (int off = 1; off < 256; off <<= 1) {
    int u = (t >= off) ? s[t - off] : 0;
    __syncthreads();
    s[t] += u;
    __syncthreads();
  }
  if (i < N) incl[i] = s[t];
  if (t == 255) bsum[blockIdx.x] = s[t];
}

__global__ void k_scan2(int* __restrict__ bsum, int nb) {
  __shared__ int s[1024];
  int t = threadIdx.x;
  int v = (t < nb) ? bsum[t] : 0;
  s[t] = v;
  __syncthreads();
  for (int off = 1; off < 1024; off <<= 1) {
    int u = (t >= off) ? s[t - off] : 0;
    __syncthreads();
    s[t] += u;
    __syncthreads();
  }
  if (t < nb) bsum[t] = s[t] - v;  // exclusive
}

__global__ void k_scan3(const int* __restrict__ cnt, const int* __restrict__ incl,
                        const int* __restrict__ bsum, int* __restrict__ rowptr,
                        float* __restrict__ dinv, int N, int E) {
  int i = blockIdx.x * 256 + threadIdx.x;
  if (i < N) {
    rowptr[i] = incl[i] - cnt[i] + bsum[i >> 8];
    dinv[i] = rsqrtf((float)cnt[i] + 1.0f);  // +1 = self loop
    if (i == N - 1) rowptr[N] = E;
  }
}

// per-(chunk,bucket) histogram; bucket = row>>9 (512 rows/bucket); NB <= 512
__global__ __launch_bounds__(256) void k_bhist(
    const void* __restrict__ ei, int E, int CH, int NB, int NBpad,
    int* __restrict__ bh, const int* __restrict__ flag) {
  __shared__ int cnt[512];
  const int k = blockIdx.x, tid = threadIdx.x;
  int is64 = *flag;
  for (int t = tid; t < NB; t += 256) cnt[t] = 0;
  __syncthreads();
  int e0 = k * CH, e1 = min(E, e0 + CH);
  for (int e = e0 + tid; e < e1; e += 256)
    atomicAdd(&cnt[edge_at(ei, e, is64) >> 9], 1);
  __syncthreads();
  for (int t = tid; t < NB; t += 256) bh[k * NBpad + t] = cnt[t];
}

// bucket starts + in-place column prefix: bh[k][b] -> absolute staged offset
__global__ __launch_bounds__(256) void k_cscan(
    int* __restrict__ bh, int* __restrict__ bstart, int NB, int NBpad, int E) {
  __shared__ int s[256];
  const int b = threadIdx.x;
  int tot = 0;
  if (b < NB)
    for (int k = 0; k < 256; ++k) tot += bh[k * NBpad + b];
  s[b] = (b < NB) ? tot : 0;
  __syncthreads();
  for (int off = 1; off < 256; off <<= 1) {
    int u = (b >= off) ? s[b - off] : 0;
    __syncthreads();
    s[b] += u;
    __syncthreads();
  }
  int excl = s[b] - tot;
  if (b < NB) {
    bstart[b] = excl;
    int run = excl;
    for (int k = 0; k < 256; ++k) {
      int t = bh[k * NBpad + b];
      bh[k * NBpad + b] = run;
      run += t;
    }
  }
  if (b == 0) bstart[NB] = E;
}

// append edges to this chunk's reserved per-bucket runs; pack (row&511)<<23|col
__global__ __launch_bounds__(256) void k_partition(
    const void* __restrict__ ei, int E, int CH, int NB, int NBpad,
    const int* __restrict__ bh, u32* __restrict__ staged,
    const int* __restrict__ flag) {
  __shared__ int cur[512];
  const int k = blockIdx.x, tid = threadIdx.x;
  int is64 = *flag;
  for (int t = tid; t < NB; t += 256) cur[t] = bh[k * NBpad + t];
  __syncthreads();
  int e0 = k * CH, e1 = min(E, e0 + CH);
  for (int e = e0 + tid; e < e1; e += 256) {
    int r = edge_at(ei, e, is64);
    int c = edge_at(ei, (long)E + e, is64);
    int pos = atomicAdd(&cur[r >> 9], 1);
    staged[pos] = ((u32)(r & 511) << 23) | (u32)c;
  }
}

// one block per bucket: scatter bucket's edges into CSR order via LDS cursors.
// All colwt writes land in the bucket's contiguous window -> full-line writes.
__global__ __launch_bounds__(1024) void k_csr_bucket(
    const u32* __restrict__ staged, const int* __restrict__ bstart,
    const int* __restrict__ rowptr, const float* __restrict__ dinv,
    int2* __restrict__ colwt, int N) {
  __shared__ int cur[512];
  __shared__ float sdv[512];
  const int b = blockIdx.x, tid = threadIdx.x;
  const int r0 = b << 9;
  for (int i = tid; i < 512; i += 1024) {
    int r = r0 + i;
    cur[i] = (r < N) ? rowptr[r] : 0;
    sdv[i] = (r < N) ? dinv[r] : 0.f;
  }
  __syncthreads();
  const int j0 = bstart[b], j1 = bstart[b + 1];
  for (int j = j0 + tid; j < j1; j += 1024) {
    u32 v = staged[j];
    int rl = v >> 23, c = v & 0x7FFFFF;
    int pos = atomicAdd(&cur[rl], 1);
    int2 o;
    o.x = c;
    o.y = __float_as_int(sdv[rl] * dinv[c]);
    colwt[pos] = o;
  }
}

// one wave per row; lane f = feature f (bf16 gather); self loop folded in
__global__ __launch_bounds__(256) void k_aggregate(
    const int* __restrict__ rowptr, const int2* __restrict__ colwt,
    const u16* __restrict__ xb, const float* __restrict__ dinv,
    u16* __restrict__ aggb, int N) {
  int r = (blockIdx.x * 256 + threadIdx.x) >> 6;
  int f = threadIdx.x & 63;
  if (r >= N) return;
  int j = rowptr[r], end = rowptr[r + 1];
  float dr = dinv[r];
  float acc = b2f(xb[(long)r * 64 + f]) * dr * dr;
  for (; j + 4 <= end; j += 4) {
    int2 e0 = colwt[j], e1 = colwt[j + 1], e2 = colwt[j + 2], e3 = colwt[j + 3];
    float x0 = b2f(xb[(long)e0.x * 64 + f]);
    float x1 = b2f(xb[(long)e1.x * 64 + f]);
    float x2 = b2f(xb[(long)e2.x * 64 + f]);
    float x3 = b2f(xb[(long)e3.x * 64 + f]);
    acc = fmaf(x0, __int_as_float(e0.y), acc);
    acc = fmaf(x1, __int_as_float(e1.y), acc);
    acc = fmaf(x2, __int_as_float(e2.y), acc);
    acc = fmaf(x3, __int_as_float(e3.y), acc);
  }
  for (; j < end; ++j) {
    int2 e0 = colwt[j];
    acc = fmaf(b2f(xb[(long)e0.x * 64 + f]), __int_as_float(e0.y), acc);
  }
  aggb[(long)r * 64 + f] = f2b(acc);
}

// fp32 -> bf16, 8 elems/thread
__global__ void k_cvt(const float* __restrict__ src, u16* __restrict__ dst, long n) {
  long i = ((long)blockIdx.x * 256 + threadIdx.x) * 8;
  if (i + 8 <= n) {
    float4 v0 = *(const float4*)(src + i);
    float4 v1 = *(const float4*)(src + i + 4);
    frag_ab o;
    o[0] = (short)f2b(v0.x); o[1] = (short)f2b(v0.y);
    o[2] = (short)f2b(v0.z); o[3] = (short)f2b(v0.w);
    o[4] = (short)f2b(v1.x); o[5] = (short)f2b(v1.y);
    o[6] = (short)f2b(v1.z); o[7] = (short)f2b(v1.w);
    *(frag_ab*)(dst + i) = o;
  }
}

// Wxp = W2x @ Wc_top ; Wap = W2a @ Wc_bot ; bp = b2x@Wc_top + b2a@Wc_bot + bc
__global__ void k_wprod(const float* __restrict__ W2x, const float* __restrict__ W2a,
                        const float* __restrict__ Wc, const float* __restrict__ b2x,
                        const float* __restrict__ b2a, const float* __restrict__ bc,
                        float* __restrict__ Wxp, float* __restrict__ Wap,
                        float* __restrict__ bp) {
  int b = blockIdx.x, t = threadIdx.x;
  if (b < 128) {
    int j = t & 127;
    bool isX = (t < 128);
    const float* wrow = isX ? (W2x + b * 128) : (W2a + b * 128);
    const float* wc = isX ? Wc : (Wc + 128 * 128);
    float s = 0.f;
    for (int m = 0; m < 128; ++m) s = fmaf(wrow[m], wc[m * 128 + j], s);
    (isX ? Wxp : Wap)[b * 128 + j] = s;
  } else if (t < 128) {
    float s = bc[t];
    for (int m = 0; m < 128; ++m)
      s += b2x[m] * Wc[m * 128 + t] + b2a[m] * Wc[(128 + m) * 128 + t];
    bp[t] = s;
  }
}

// pack W[K][Nc] fp32 row-major into bf16 B-fragment-linear order
__global__ void k_pack(const float* __restrict__ W, u16* __restrict__ dst,
                       int K, int Nc) {
  int i = blockIdx.x * 256 + threadIdx.x;
  if (i >= K * Nc) return;
  int b = i & 7, l = (i >> 3) & 63, f = i >> 9;
  int KB = K >> 5;
  int kb = f % KB, nb = f / KB;
  int k = kb * 32 + (l >> 4) * 8 + b;
  int n = nb * 16 + (l & 15);
  dst[i] = f2b(W[k * Nc + n]);
}

// ---------------------------------------------------------------------------
// Fused MLP (unchanged)
// ---------------------------------------------------------------------------
__global__ __launch_bounds__(256) void k_mlp(
    const u16* __restrict__ xb, const u16* __restrict__ aggb,
    const u16* __restrict__ W1xf, const u16* __restrict__ W1af,
    const float* __restrict__ b1x, const float* __restrict__ b1a,
    const u16* __restrict__ Wxpf, const u16* __restrict__ Wapf,
    const float* __restrict__ bp,
    const u16* __restrict__ Wclsf, const float* __restrict__ bcls,
    float* __restrict__ out, int N) {
  __shared__ u16 H1[4][16 * 256];   // 32KB
  __shared__ u16 H2[4][16 * 128];   // 16KB
  const int w = threadIdx.x >> 6;
  const int lane = threadIdx.x & 63;
  const int m0 = blockIdx.x * 64 + w * 16;
  const int lm = lane & 15;
  const int lq = lane >> 4;
  u16* h1 = H1[w];
  u16* h2 = H2[w];

  for (int br = 0; br < 2; ++br) {
    const u16* A = br ? aggb : xb;
    const u16* Wf = br ? W1af : W1xf;
    const float* bias = br ? b1a : b1x;
    const u16* ap = A + (long)(m0 + lm) * 64 + lq * 8;
    frag_ab a0 = *(const frag_ab*)(ap);
    frag_ab a1 = *(const frag_ab*)(ap + 32);
#pragma unroll
    for (int nb = 0; nb < 8; ++nb) {
      frag_ab b0 = *(const frag_ab*)(Wf + (size_t)((nb * 2 + 0) * 64 + lane) * 8);
      frag_ab b1v = *(const frag_ab*)(Wf + (size_t)((nb * 2 + 1) * 64 + lane) * 8);
      f32x4 acc = {0.f, 0.f, 0.f, 0.f};
      acc = __builtin_amdgcn_mfma_f32_16x16x32_bf16(a0, b0, acc, 0, 0, 0);
      acc = __builtin_amdgcn_mfma_f32_16x16x32_bf16(a1, b1v, acc, 0, 0, 0);
      int col = nb * 16 + lm;
      float bv = bias[col];
#pragma unroll
      for (int r = 0; r < 4; ++r) {
        int row = lq * 4 + r;
        h1[(row * 256 + br * 128 + col) ^ ((row & 7) << 3)] =
            f2b(fmaxf(acc[r] + bv, 0.f));
      }
    }
  }
  __syncthreads();

  frag_ab hfr[8];
#pragma unroll
  for (int kb = 0; kb < 8; ++kb)
    hfr[kb] = *(const frag_ab*)&h1[(lm * 256 + kb * 32 + lq * 8) ^ ((lm & 7) << 3)];
#pragma unroll
  for (int nb = 0; nb < 8; ++nb) {
    f32x4 acc = {0.f, 0.f, 0.f, 0.f};
#pragma unroll
    for (int kb = 0; kb < 8; ++kb) {
      const u16* Wf2 = (kb < 4) ? Wxpf : Wapf;
      frag_ab b = *(const frag_ab*)(Wf2 + (size_t)((nb * 4 + (kb & 3)) * 64 + lane) * 8);
      acc = __builtin_amdgcn_mfma_f32_16x16x32_bf16(hfr[kb], b, acc, 0, 0, 0);
    }
    int col = nb * 16 + lm;
    float bv = bp[col];
#pragma unroll
    for (int r = 0; r < 4; ++r) {
      int row = lq * 4 + r;
      h2[(row * 128 + col) ^ ((row & 7) << 3)] = f2b(fmaxf(acc[r] + bv, 0.f));
    }
  }
  __syncthreads();

  frag_ab h3[4];
#pragma unroll
  for (int kb = 0; kb < 4; ++kb)
    h3[kb] = *(const frag_ab*)&h2[(lm * 128 + kb * 32 + lq * 8) ^ ((lm & 7) << 3)];
#pragma unroll
  for (int nb = 0; nb < 4; ++nb) {
    f32x4 acc = {0.f, 0.f, 0.f, 0.f};
#pragma unroll
    for (int kb = 0; kb < 4; ++kb) {
      frag_ab b = *(const frag_ab*)(Wclsf + (size_t)((nb * 4 + kb) * 64 + lane) * 8);
      acc = __builtin_amdgcn_mfma_f32_16x16x32_bf16(h3[kb], b, acc, 0, 0, 0);
    }
    int col = nb * 16 + lm;
    float bv = bcls[col];
#pragma unroll
    for (int r = 0; r < 4; ++r) {
      int grow = m0 + lq * 4 + r;
      if (grow < N) out[(long)grow * 64 + col] = acc[r] + bv;
    }
  }
}

extern "C" void kernel_launch(void* const* d_in, const int* in_sizes, int n_in,
                              void* d_out, int out_size, void* d_ws, size_t ws_size,
                              hipStream_t stream) {
  const float* x    = (const float*)d_in[0];
  const void*  ei   = d_in[1];
  const float* W1x  = (const float*)d_in[2];
  const float* b1x  = (const float*)d_in[3];
  const float* W2x  = (const float*)d_in[4];
  const float* b2x  = (const float*)d_in[5];
  const float* W1a  = (const float*)d_in[6];
  const float* b1a  = (const float*)d_in[7];
  const float* W2a  = (const float*)d_in[8];
  const float* b2a  = (const float*)d_in[9];
  const float* Wc   = (const float*)d_in[10];
  const float* bc   = (const float*)d_in[11];
  const float* Wcls = (const float*)d_in[12];
  const float* bcls = (const float*)d_in[13];
  const int N = in_sizes[0] / 64;
  const int E = in_sizes[1] / 2;

  const int NB = (N + 511) >> 9;          // 512 rows per bucket
  const int NBpad = (NB + 63) & ~63;
  const int CH = (E + 255) / 256;

  float* ws = (float*)d_ws;
  long nAlign = (N + 255) & ~255L;
  float* dinv = ws;                                    // N
  int*   cntI = (int*)(ws + nAlign);                   // N
  int*   incl = (int*)(ws + 2 * nAlign);               // N
  int*   rowptr = (int*)(ws + 3 * nAlign);             // N+1
  int*   bsum = (int*)(ws + 4 * nAlign + 256);         // 1024
  int*   flag = bsum + 1024;                           // 1
  u16*   xb   = (u16*)(bsum + 2048);                   // N*64 bf16
  u16*   aggb = xb + (long)N * 64;                     // N*64 bf16
  float* Wxp  = (float*)(aggb + (long)N * 64);         // 16384
  float* Wap  = Wxp + 16384;                           // 16384
  float* bp   = Wap + 16384;                           // 128
  u16*   W1xf = (u16*)(bp + 128);                      // 8192
  u16*   W1af = W1xf + 8192;                           // 8192
  u16*   Wxpf = W1af + 8192;                           // 16384
  u16*   Wapf = Wxpf + 16384;                          // 16384
  u16*   Wclsf = Wapf + 16384;                         // 8192
  int*   bh   = (int*)(Wclsf + 8192);                  // 256*NBpad
  int*   bstart = bh + 256 * NBpad;                    // NB+1 (+pad)
  u32*   staged = (u32*)(bstart + NB + 64);            // E
  int2*  colwt  = (int2*)(((uintptr_t)(staged + E) + 15) & ~(uintptr_t)15);  // E
  float* out = (float*)d_out;

  const int nb = (N + 255) / 256;
  k_detect<<<1, 64, 0, stream>>>((const int*)ei, flag);
  k_zero<<<nb, 256, 0, stream>>>(cntI, N);
  k_hist<<<(E + 255) / 256, 256, 0, stream>>>(ei, E, cntI, flag);
  k_scan1<<<nb, 256, 0, stream>>>(cntI, incl, bsum, N);
  k_scan2<<<1, 1024, 0, stream>>>(bsum, nb);
  k_scan3<<<nb, 256, 0, stream>>>(cntI, incl, bsum, rowptr, dinv, N, E);
  k_cvt<<<(int)(((long)N * 64 / 8 + 255) / 256), 256, 0, stream>>>(x, xb, (long)N * 64);
  k_bhist<<<256, 256, 0, stream>>>(ei, E, CH, NB, NBpad, bh, flag);
  k_cscan<<<1, 256, 0, stream>>>(bh, bstart, NB, NBpad, E);
  k_partition<<<256, 256, 0, stream>>>(ei, E, CH, NB, NBpad, bh, staged, flag);
  k_csr_bucket<<<NB, 1024, 0, stream>>>(staged, bstart, rowptr, dinv, colwt, N);
  k_aggregate<<<(N * 64 + 255) / 256, 256, 0, stream>>>(rowptr, colwt, xb, dinv, aggb, N);
  k_wprod<<<129, 256, 0, stream>>>(W2x, W2a, Wc, b2x, b2a, bc, Wxp, Wap, bp);
  k_pack<<<32, 256, 0, stream>>>(W1x, W1xf, 64, 128);
  k_pack<<<32, 256, 0, stream>>>(W1a, W1af, 64, 128);
  k_pack<<<64, 256, 0, stream>>>(Wxp, Wxpf, 128, 128);
  k_pack<<<64, 256, 0, stream>>>(Wap, Wapf, 128, 128);
  k_pack<<<32, 256, 0, stream>>>(Wcls, Wclsf, 128, 64);
  k_mlp<<<(N + 63) / 64, 256, 0, stream>>>(xb, aggb, W1xf, W1af, b1x, b1a,
                                           Wxpf, Wapf, bp, Wclsf, bcls, out, N);
}

// Round 6
// 172.760 us; speedup vs baseline: 4.1939x; 1.4292x over previous
//
#include <hip/hip_runtime.h>
#include <stdint.h>

typedef unsigned short u16;
typedef unsigned int u32;
typedef __attribute__((ext_vector_type(8))) short frag_ab;   // 8 bf16
typedef __attribute__((ext_vector_type(4))) float f32x4;

__device__ __forceinline__ u16 f2b(float f) {
  unsigned u = __float_as_uint(f);
  return (u16)((u + 0x7fffu + ((u >> 16) & 1u)) >> 16);
}
__device__ __forceinline__ float b2f(u16 u) {
  return __uint_as_float(((unsigned)u) << 16);
}

// ---------------------------------------------------------------------------

__global__ void k_detect(const int* __restrict__ ei, int* __restrict__ flag) {
  int t = threadIdx.x;  // 64 threads
  int v = ei[2 * t + 1];
  unsigned long long b = __ballot(v == 0);
  if (t == 0) *flag = (b == ~0ULL) ? 1 : 0;
}

__device__ __forceinline__ int edge_at(const void* ei, long pos, int is64) {
  if (is64) return (int)((const long long*)ei)[pos];
  return ((const int*)ei)[pos];
}

// per-(chunk,bucket) histogram (bucket = row>>9) + fused fp32->bf16 convert of x
__global__ __launch_bounds__(256) void k_bhist_cvt(
    const void* __restrict__ ei, int E, int CH, int NB, int NBpad,
    int* __restrict__ bh, const int* __restrict__ flag,
    const float* __restrict__ x, u16* __restrict__ xb, long n64) {
  __shared__ int cnt[512];
  const int k = blockIdx.x, tid = threadIdx.x;
  // ---- fused convert (grid-stride over 65536 threads)
  for (long i = ((long)k * 256 + tid) * 8; i < n64; i += 65536L * 8) {
    float4 v0 = *(const float4*)(x + i);
    float4 v1 = *(const float4*)(x + i + 4);
    frag_ab o;
    o[0] = (short)f2b(v0.x); o[1] = (short)f2b(v0.y);
    o[2] = (short)f2b(v0.z); o[3] = (short)f2b(v0.w);
    o[4] = (short)f2b(v1.x); o[5] = (short)f2b(v1.y);
    o[6] = (short)f2b(v1.z); o[7] = (short)f2b(v1.w);
    *(frag_ab*)(xb + i) = o;
  }
  // ---- bucket histogram
  int is64 = *flag;
  for (int t = tid; t < NB; t += 256) cnt[t] = 0;
  __syncthreads();
  int e0 = k * CH, e1 = min(E, e0 + CH);
  for (int e = e0 + tid; e < e1; e += 256)
    atomicAdd(&cnt[edge_at(ei, e, is64) >> 9], 1);
  __syncthreads();
  for (int t = tid; t < NB; t += 256) bh[k * NBpad + t] = cnt[t];
}

// bucket starts + in-place column prefix: bh[k][b] -> absolute staged offset
__global__ __launch_bounds__(256) void k_cscan(
    int* __restrict__ bh, int* __restrict__ bstart, int NB, int NBpad, int E) {
  __shared__ int s[256];
  const int b = threadIdx.x;
  int tot = 0;
  if (b < NB)
    for (int k = 0; k < 256; ++k) tot += bh[k * NBpad + b];
  s[b] = (b < NB) ? tot : 0;
  __syncthreads();
  for (int off = 1; off < 256; off <<= 1) {
    int u = (b >= off) ? s[b - off] : 0;
    __syncthreads();
    s[b] += u;
    __syncthreads();
  }
  int excl = s[b] - tot;
  if (b < NB) {
    bstart[b] = excl;
    int run = excl;
    for (int k = 0; k < 256; ++k) {
      int t = bh[k * NBpad + b];
      bh[k * NBpad + b] = run;
      run += t;
    }
  }
  if (b == 0) bstart[NB] = E;
}

// append edges to this chunk's reserved per-bucket runs; pack (row&511)<<23|col
__global__ __launch_bounds__(256) void k_partition(
    const void* __restrict__ ei, int E, int CH, int NB, int NBpad,
    const int* __restrict__ bh, u32* __restrict__ staged,
    const int* __restrict__ flag) {
  __shared__ int cur[512];
  const int k = blockIdx.x, tid = threadIdx.x;
  int is64 = *flag;
  for (int t = tid; t < NB; t += 256) cur[t] = bh[k * NBpad + t];
  __syncthreads();
  int e0 = k * CH, e1 = min(E, e0 + CH);
  for (int e = e0 + tid; e < e1; e += 256) {
    int r = edge_at(ei, e, is64);
    int c = edge_at(ei, (long)E + e, is64);
    int pos = atomicAdd(&cur[r >> 9], 1);
    staged[pos] = ((u32)(r & 511) << 23) | (u32)c;
  }
}

// one block per bucket: local degree histogram -> rowptr/dinv, then scatter
// cols into CSR order. All writes land in the bucket's contiguous windows.
__global__ __launch_bounds__(1024) void k_csr_bucket(
    const u32* __restrict__ staged, const int* __restrict__ bstart,
    int* __restrict__ rowptr, float* __restrict__ dinv,
    u32* __restrict__ cols, int N, int E) {
  __shared__ int cnt[512];
  __shared__ int cur[512];
  const int b = blockIdx.x, tid = threadIdx.x;
  const int r0 = b << 9;
  if (tid < 512) cnt[tid] = 0;
  __syncthreads();
  const int j0 = bstart[b], j1 = bstart[b + 1];
  for (int j = j0 + tid; j < j1; j += 1024)
    atomicAdd(&cnt[staged[j] >> 23], 1);
  __syncthreads();
  // exclusive scan over 512 degree counts (first 512 threads)
  if (tid < 512) cur[tid] = cnt[tid];
  __syncthreads();
  for (int off = 1; off < 512; off <<= 1) {
    int v = 0;
    if (tid < 512 && tid >= off) v = cur[tid - off];
    __syncthreads();
    if (tid < 512) cur[tid] += v;
    __syncthreads();
  }
  int myStart = 0;
  if (tid < 512) {
    myStart = j0 + cur[tid] - cnt[tid];
    int r = r0 + tid;
    if (r < N) {
      rowptr[r] = myStart;
      dinv[r] = rsqrtf((float)cnt[tid] + 1.0f);  // +1 = self loop
    }
  }
  __syncthreads();
  if (tid < 512) cur[tid] = myStart;
  if (b == 0 && tid == 0) rowptr[N] = E;
  __syncthreads();
  for (int j = j0 + tid; j < j1; j += 1024) {
    u32 v = staged[j];
    int rl = v >> 23;
    int pos = atomicAdd(&cur[rl], 1);
    cols[pos] = v & 0x7FFFFF;
  }
}

// one wave per row; lane f = feature f; weights dinv[c] on the fly;
// result = dr * (x_r*dr + sum_c x_c*dinv_c)
__global__ __launch_bounds__(256) void k_aggregate(
    const int* __restrict__ rowptr, const u32* __restrict__ cols,
    const u16* __restrict__ xb, const float* __restrict__ dinv,
    u16* __restrict__ aggb, int N) {
  int r = (blockIdx.x * 256 + threadIdx.x) >> 6;
  int f = threadIdx.x & 63;
  if (r >= N) return;
  int j = rowptr[r], end = rowptr[r + 1];
  float dr = dinv[r];
  float acc = b2f(xb[(long)r * 64 + f]) * dr;
  for (; j + 4 <= end; j += 4) {
    int c0 = cols[j], c1 = cols[j + 1], c2 = cols[j + 2], c3 = cols[j + 3];
    float w0 = dinv[c0], w1 = dinv[c1], w2 = dinv[c2], w3 = dinv[c3];
    float x0 = b2f(xb[(long)c0 * 64 + f]);
    float x1 = b2f(xb[(long)c1 * 64 + f]);
    float x2 = b2f(xb[(long)c2 * 64 + f]);
    float x3 = b2f(xb[(long)c3 * 64 + f]);
    acc = fmaf(x0, w0, acc);
    acc = fmaf(x1, w1, acc);
    acc = fmaf(x2, w2, acc);
    acc = fmaf(x3, w3, acc);
  }
  for (; j < end; ++j) {
    int c = cols[j];
    acc = fmaf(b2f(xb[(long)c * 64 + f]), dinv[c], acc);
  }
  aggb[(long)r * 64 + f] = f2b(acc * dr);
}

// Wxp = W2x @ Wc_top ; Wap = W2a @ Wc_bot ; bp = b2x@Wc_top + b2a@Wc_bot + bc
__global__ void k_wprod(const float* __restrict__ W2x, const float* __restrict__ W2a,
                        const float* __restrict__ Wc, const float* __restrict__ b2x,
                        const float* __restrict__ b2a, const float* __restrict__ bc,
                        float* __restrict__ Wxp, float* __restrict__ Wap,
                        float* __restrict__ bp) {
  int b = blockIdx.x, t = threadIdx.x;
  if (b < 128) {
    int j = t & 127;
    bool isX = (t < 128);
    const float* wrow = isX ? (W2x + b * 128) : (W2a + b * 128);
    const float* wc = isX ? Wc : (Wc + 128 * 128);
    float s = 0.f;
    for (int m = 0; m < 128; ++m) s = fmaf(wrow[m], wc[m * 128 + j], s);
    (isX ? Wxp : Wap)[b * 128 + j] = s;
  } else if (t < 128) {
    float s = bc[t];
    for (int m = 0; m < 128; ++m)
      s += b2x[m] * Wc[m * 128 + t] + b2a[m] * Wc[(128 + m) * 128 + t];
    bp[t] = s;
  }
}

// all 5 weight packs in one launch; blockIdx ranges select the weight
__global__ void k_packall(
    const float* __restrict__ W1x, const float* __restrict__ W1a,
    const float* __restrict__ Wxp, const float* __restrict__ Wap,
    const float* __restrict__ Wcls,
    u16* __restrict__ W1xf, u16* __restrict__ W1af,
    u16* __restrict__ Wxpf, u16* __restrict__ Wapf, u16* __restrict__ Wclsf) {
  int blk = blockIdx.x;
  const float* W;
  u16* dst;
  int K, Nc, i0;
  if (blk < 32)       { W = W1x;  dst = W1xf;  K = 64;  Nc = 128; i0 = blk; }
  else if (blk < 64)  { W = W1a;  dst = W1af;  K = 64;  Nc = 128; i0 = blk - 32; }
  else if (blk < 128) { W = Wxp;  dst = Wxpf;  K = 128; Nc = 128; i0 = blk - 64; }
  else if (blk < 192) { W = Wap;  dst = Wapf;  K = 128; Nc = 128; i0 = blk - 128; }
  else                { W = Wcls; dst = Wclsf; K = 128; Nc = 64;  i0 = blk - 192; }
  int i = i0 * 256 + threadIdx.x;
  if (i >= K * Nc) return;
  int b = i & 7, l = (i >> 3) & 63, f = i >> 9;
  int KB = K >> 5;
  int kb = f % KB, nb = f / KB;
  int k = kb * 32 + (l >> 4) * 8 + b;
  int n = nb * 16 + (l & 15);
  dst[i] = f2b(W[k * Nc + n]);
}

// ---------------------------------------------------------------------------
// Fused MLP (unchanged)
// ---------------------------------------------------------------------------
__global__ __launch_bounds__(256) void k_mlp(
    const u16* __restrict__ xb, const u16* __restrict__ aggb,
    const u16* __restrict__ W1xf, const u16* __restrict__ W1af,
    const float* __restrict__ b1x, const float* __restrict__ b1a,
    const u16* __restrict__ Wxpf, const u16* __restrict__ Wapf,
    const float* __restrict__ bp,
    const u16* __restrict__ Wclsf, const float* __restrict__ bcls,
    float* __restrict__ out, int N) {
  __shared__ u16 H1[4][16 * 256];   // 32KB
  __shared__ u16 H2[4][16 * 128];   // 16KB
  const int w = threadIdx.x >> 6;
  const int lane = threadIdx.x & 63;
  const int m0 = blockIdx.x * 64 + w * 16;
  const int lm = lane & 15;
  const int lq = lane >> 4;
  u16* h1 = H1[w];
  u16* h2 = H2[w];

  for (int br = 0; br < 2; ++br) {
    const u16* A = br ? aggb : xb;
    const u16* Wf = br ? W1af : W1xf;
    const float* bias = br ? b1a : b1x;
    const u16* ap = A + (long)(m0 + lm) * 64 + lq * 8;
    frag_ab a0 = *(const frag_ab*)(ap);
    frag_ab a1 = *(const frag_ab*)(ap + 32);
#pragma unroll
    for (int nb = 0; nb < 8; ++nb) {
      frag_ab b0 = *(const frag_ab*)(Wf + (size_t)((nb * 2 + 0) * 64 + lane) * 8);
      frag_ab b1v = *(const frag_ab*)(Wf + (size_t)((nb * 2 + 1) * 64 + lane) * 8);
      f32x4 acc = {0.f, 0.f, 0.f, 0.f};
      acc = __builtin_amdgcn_mfma_f32_16x16x32_bf16(a0, b0, acc, 0, 0, 0);
      acc = __builtin_amdgcn_mfma_f32_16x16x32_bf16(a1, b1v, acc, 0, 0, 0);
      int col = nb * 16 + lm;
      float bv = bias[col];
#pragma unroll
      for (int r = 0; r < 4; ++r) {
        int row = lq * 4 + r;
        h1[(row * 256 + br * 128 + col) ^ ((row & 7) << 3)] =
            f2b(fmaxf(acc[r] + bv, 0.f));
      }
    }
  }
  __syncthreads();

  frag_ab hfr[8];
#pragma unroll
  for (int kb = 0; kb < 8; ++kb)
    hfr[kb] = *(const frag_ab*)&h1[(lm * 256 + kb * 32 + lq * 8) ^ ((lm & 7) << 3)];
#pragma unroll
  for (int nb = 0; nb < 8; ++nb) {
    f32x4 acc = {0.f, 0.f, 0.f, 0.f};
#pragma unroll
    for (int kb = 0; kb < 8; ++kb) {
      const u16* Wf2 = (kb < 4) ? Wxpf : Wapf;
      frag_ab b = *(const frag_ab*)(Wf2 + (size_t)((nb * 4 + (kb & 3)) * 64 + lane) * 8);
      acc = __builtin_amdgcn_mfma_f32_16x16x32_bf16(hfr[kb], b, acc, 0, 0, 0);
    }
    int col = nb * 16 + lm;
    float bv = bp[col];
#pragma unroll
    for (int r = 0; r < 4; ++r) {
      int row = lq * 4 + r;
      h2[(row * 128 + col) ^ ((row & 7) << 3)] = f2b(fmaxf(acc[r] + bv, 0.f));
    }
  }
  __syncthreads();

  frag_ab h3[4];
#pragma unroll
  for (int kb = 0; kb < 4; ++kb)
    h3[kb] = *(const frag_ab*)&h2[(lm * 128 + kb * 32 + lq * 8) ^ ((lm & 7) << 3)];
#pragma unroll
  for (int nb = 0; nb < 4; ++nb) {
    f32x4 acc = {0.f, 0.f, 0.f, 0.f};
#pragma unroll
    for (int kb = 0; kb < 4; ++kb) {
      frag_ab b = *(const frag_ab*)(Wclsf + (size_t)((nb * 4 + kb) * 64 + lane) * 8);
      acc = __builtin_amdgcn_mfma_f32_16x16x32_bf16(h3[kb], b, acc, 0, 0, 0);
    }
    int col = nb * 16 + lm;
    float bv = bcls[col];
#pragma unroll
    for (int r = 0; r < 4; ++r) {
      int grow = m0 + lq * 4 + r;
      if (grow < N) out[(long)grow * 64 + col] = acc[r] + bv;
    }
  }
}

extern "C" void kernel_launch(void* const* d_in, const int* in_sizes, int n_in,
                              void* d_out, int out_size, void* d_ws, size_t ws_size,
                              hipStream_t stream) {
  const float* x    = (const float*)d_in[0];
  const void*  ei   = d_in[1];
  const float* W1x  = (const float*)d_in[2];
  const float* b1x  = (const float*)d_in[3];
  const float* W2x  = (const float*)d_in[4];
  const float* b2x  = (const float*)d_in[5];
  const float* W1a  = (const float*)d_in[6];
  const float* b1a  = (const float*)d_in[7];
  const float* W2a  = (const float*)d_in[8];
  const float* b2a  = (const float*)d_in[9];
  const float* Wc   = (const float*)d_in[10];
  const float* bc   = (const float*)d_in[11];
  const float* Wcls = (const float*)d_in[12];
  const float* bcls = (const float*)d_in[13];
  const int N = in_sizes[0] / 64;
  const int E = in_sizes[1] / 2;

  const int NB = (N + 511) >> 9;          // 512 rows per bucket
  const int NBpad = (NB + 63) & ~63;
  const int CH = (E + 255) / 256;

  float* ws = (float*)d_ws;
  long nAlign = (N + 255) & ~255L;
  float* dinv = ws;                                    // N
  int*   rowptr = (int*)(ws + nAlign);                 // N+1
  int*   flag = (int*)(ws + 2 * nAlign + 256);         // 1
  u16*   xb   = (u16*)(ws + 2 * nAlign + 512);         // N*64 bf16
  u16*   aggb = xb + (long)N * 64;                     // N*64 bf16
  float* Wxp  = (float*)(aggb + (long)N * 64);         // 16384
  float* Wap  = Wxp + 16384;                           // 16384
  float* bp   = Wap + 16384;                           // 128
  u16*   W1xf = (u16*)(bp + 128);                      // 8192
  u16*   W1af = W1xf + 8192;                           // 8192
  u16*   Wxpf = W1af + 8192;                           // 16384
  u16*   Wapf = Wxpf + 16384;                          // 16384
  u16*   Wclsf = Wapf + 16384;                         // 8192
  int*   bh   = (int*)(Wclsf + 8192);                  // 256*NBpad
  int*   bstart = bh + 256 * NBpad;                    // NB+1 (+pad)
  u32*   staged = (u32*)(bstart + NB + 64);            // E
  u32*   cols   = staged + E;                          // E
  float* out = (float*)d_out;

  k_detect<<<1, 64, 0, stream>>>((const int*)ei, flag);
  k_bhist_cvt<<<256, 256, 0, stream>>>(ei, E, CH, NB, NBpad, bh, flag,
                                       x, xb, (long)N * 64);
  k_cscan<<<1, 256, 0, stream>>>(bh, bstart, NB, NBpad, E);
  k_partition<<<256, 256, 0, stream>>>(ei, E, CH, NB, NBpad, bh, staged, flag);
  k_csr_bucket<<<NB, 1024, 0, stream>>>(staged, bstart, rowptr, dinv, cols, N, E);
  k_aggregate<<<(N * 64 + 255) / 256, 256, 0, stream>>>(rowptr, cols, xb, dinv, aggb, N);
  k_wprod<<<129, 256, 0, stream>>>(W2x, W2a, Wc, b2x, b2a, bc, Wxp, Wap, bp);
  k_packall<<<224, 256, 0, stream>>>(W1x, W1a, Wxp, Wap, Wcls,
                                     W1xf, W1af, Wxpf, Wapf, Wclsf);
  k_mlp<<<(N + 63) / 64, 256, 0, stream>>>(xb, aggb, W1xf, W1af, b1x, b1a,
                                           Wxpf, Wapf, bp, Wclsf, bcls, out, N);
}

// Round 7
// 157.743 us; speedup vs baseline: 4.5932x; 1.0952x over previous
//
#include <hip/hip_runtime.h>
#include <stdint.h>

typedef unsigned short u16;
typedef unsigned int u32;
typedef __attribute__((ext_vector_type(8))) short frag_ab;   // 8 bf16
typedef __attribute__((ext_vector_type(4))) float f32x4;

__device__ __forceinline__ u16 f2b(float f) {
  unsigned u = __float_as_uint(f);
  return (u16)((u + 0x7fffu + ((u >> 16) & 1u)) >> 16);
}
__device__ __forceinline__ float b2f(u16 u) {
  return __uint_as_float(((unsigned)u) << 16);
}

// all-wave inline int64 detection: odd int32 slots of first 64 elems all zero
__device__ __forceinline__ int detect64(const int* __restrict__ ei32) {
  int v = ei32[2 * (threadIdx.x & 63) + 1];
  unsigned long long b = __ballot(v == 0);
  return (b == ~0ULL) ? 1 : 0;
}

__device__ __forceinline__ int edge_at(const void* ei, long pos, int is64) {
  if (is64) return (int)((const long long*)ei)[pos];
  return ((const int*)ei)[pos];
}

// ---------------------------------------------------------------------------
// per-(chunk,bucket) histogram (bucket = row>>9) + fused fp32->bf16 convert
__global__ __launch_bounds__(256) void k_bhist_cvt(
    const void* __restrict__ ei, int E, int CH, int NB, int NBpad,
    int* __restrict__ bh,
    const float* __restrict__ x, u16* __restrict__ xb, long n64) {
  __shared__ int cnt[512];
  const int k = blockIdx.x, tid = threadIdx.x;
  const int is64 = detect64((const int*)ei);
  // ---- fused convert (grid-stride over 65536 threads)
  for (long i = ((long)k * 256 + tid) * 8; i < n64; i += 65536L * 8) {
    float4 v0 = *(const float4*)(x + i);
    float4 v1 = *(const float4*)(x + i + 4);
    frag_ab o;
    o[0] = (short)f2b(v0.x); o[1] = (short)f2b(v0.y);
    o[2] = (short)f2b(v0.z); o[3] = (short)f2b(v0.w);
    o[4] = (short)f2b(v1.x); o[5] = (short)f2b(v1.y);
    o[6] = (short)f2b(v1.z); o[7] = (short)f2b(v1.w);
    *(frag_ab*)(xb + i) = o;
  }
  // ---- bucket histogram
  for (int t = tid; t < NB; t += 256) cnt[t] = 0;
  __syncthreads();
  int e0 = k * CH, e1 = min(E, e0 + CH);
  for (int e = e0 + tid; e < e1; e += 256)
    atomicAdd(&cnt[edge_at(ei, e, is64) >> 9], 1);
  __syncthreads();
  for (int t = tid; t < NB; t += 256) bh[k * NBpad + t] = cnt[t];
}

// bucket starts + in-place column prefix: bh[k][b] -> absolute staged offset
__global__ __launch_bounds__(256) void k_cscan(
    int* __restrict__ bh, int* __restrict__ bstart, int NB, int NBpad, int E) {
  __shared__ int s[256];
  const int b = threadIdx.x;
  int tot = 0;
  if (b < NB)
    for (int k = 0; k < 256; ++k) tot += bh[k * NBpad + b];
  s[b] = (b < NB) ? tot : 0;
  __syncthreads();
  for (int off = 1; off < 256; off <<= 1) {
    int u = (b >= off) ? s[b - off] : 0;
    __syncthreads();
    s[b] += u;
    __syncthreads();
  }
  int excl = s[b] - tot;
  if (b < NB) {
    bstart[b] = excl;
    int run = excl;
    for (int k = 0; k < 256; ++k) {
      int t = bh[k * NBpad + b];
      bh[k * NBpad + b] = run;
      run += t;
    }
  }
  if (b == 0) bstart[NB] = E;
}

// append edges to this chunk's reserved per-bucket runs; pack (row&511)<<23|col
__global__ __launch_bounds__(256) void k_partition(
    const void* __restrict__ ei, int E, int CH, int NB, int NBpad,
    const int* __restrict__ bh, u32* __restrict__ staged) {
  __shared__ int cur[512];
  const int k = blockIdx.x, tid = threadIdx.x;
  const int is64 = detect64((const int*)ei);
  for (int t = tid; t < NB; t += 256) cur[t] = bh[k * NBpad + t];
  __syncthreads();
  int e0 = k * CH, e1 = min(E, e0 + CH);
  for (int e = e0 + tid; e < e1; e += 256) {
    int r = edge_at(ei, e, is64);
    int c = edge_at(ei, (long)E + e, is64);
    int pos = atomicAdd(&cur[r >> 9], 1);
    staged[pos] = ((u32)(r & 511) << 23) | (u32)c;
  }
}

// one block per bucket: local degree histogram -> rowptr/dinv, then scatter
// cols into CSR order. All writes land in the bucket's contiguous windows.
__global__ __launch_bounds__(1024) void k_csr_bucket(
    const u32* __restrict__ staged, const int* __restrict__ bstart,
    int* __restrict__ rowptr, float* __restrict__ dinv,
    u32* __restrict__ cols, int N, int E) {
  __shared__ int cnt[512];
  __shared__ int cur[512];
  const int b = blockIdx.x, tid = threadIdx.x;
  const int r0 = b << 9;
  if (tid < 512) cnt[tid] = 0;
  __syncthreads();
  const int j0 = bstart[b], j1 = bstart[b + 1];
  for (int j = j0 + tid; j < j1; j += 1024)
    atomicAdd(&cnt[staged[j] >> 23], 1);
  __syncthreads();
  if (tid < 512) cur[tid] = cnt[tid];
  __syncthreads();
  for (int off = 1; off < 512; off <<= 1) {
    int v = 0;
    if (tid < 512 && tid >= off) v = cur[tid - off];
    __syncthreads();
    if (tid < 512) cur[tid] += v;
    __syncthreads();
  }
  int myStart = 0;
  if (tid < 512) {
    myStart = j0 + cur[tid] - cnt[tid];
    int r = r0 + tid;
    if (r < N) {
      rowptr[r] = myStart;
      dinv[r] = rsqrtf((float)cnt[tid] + 1.0f);  // +1 = self loop
    }
  }
  __syncthreads();
  if (tid < 512) cur[tid] = myStart;
  if (b == 0 && tid == 0) rowptr[N] = E;
  __syncthreads();
  for (int j = j0 + tid; j < j1; j += 1024) {
    u32 v = staged[j];
    int rl = v >> 23;
    int pos = atomicAdd(&cur[rl], 1);
    cols[pos] = v & 0x7FFFFF;
  }
}

// TWO rows per wave (independent gather chains -> 8 outstanding loads);
// lane f = feature f; result = dr * (x_r*dr + sum_c x_c*dinv_c)
__global__ __launch_bounds__(256) void k_aggregate(
    const int* __restrict__ rowptr, const u32* __restrict__ cols,
    const u16* __restrict__ xb, const float* __restrict__ dinv,
    u16* __restrict__ aggb, int N) {
  int q = (blockIdx.x * 256 + threadIdx.x) >> 6;   // wave id
  int f = threadIdx.x & 63;
  int r0 = q * 2, r1 = q * 2 + 1;
  if (r0 >= N) return;
  const bool has1 = (r1 < N);
  int j0 = rowptr[r0], e0 = rowptr[r0 + 1];
  int j1 = has1 ? rowptr[r1] : 0;
  int e1 = has1 ? rowptr[r1 + 1] : 0;
  float d0 = dinv[r0];
  float d1 = has1 ? dinv[r1] : 0.f;
  float acc0 = b2f(xb[(long)r0 * 64 + f]) * d0;
  float acc1 = has1 ? b2f(xb[(long)r1 * 64 + f]) * d1 : 0.f;
  // dual-chain main loop: 8 gathers in flight
  while (j0 + 4 <= e0 && j1 + 4 <= e1) {
    int ca0 = cols[j0], ca1 = cols[j0 + 1], ca2 = cols[j0 + 2], ca3 = cols[j0 + 3];
    int cb0 = cols[j1], cb1 = cols[j1 + 1], cb2 = cols[j1 + 2], cb3 = cols[j1 + 3];
    float xa0 = b2f(xb[(long)ca0 * 64 + f]);
    float xa1 = b2f(xb[(long)ca1 * 64 + f]);
    float xa2 = b2f(xb[(long)ca2 * 64 + f]);
    float xa3 = b2f(xb[(long)ca3 * 64 + f]);
    float xb0 = b2f(xb[(long)cb0 * 64 + f]);
    float xb1 = b2f(xb[(long)cb1 * 64 + f]);
    float xb2 = b2f(xb[(long)cb2 * 64 + f]);
    float xb3 = b2f(xb[(long)cb3 * 64 + f]);
    float wa0 = dinv[ca0], wa1 = dinv[ca1], wa2 = dinv[ca2], wa3 = dinv[ca3];
    float wb0 = dinv[cb0], wb1 = dinv[cb1], wb2 = dinv[cb2], wb3 = dinv[cb3];
    acc0 = fmaf(xa0, wa0, acc0); acc1 = fmaf(xb0, wb0, acc1);
    acc0 = fmaf(xa1, wa1, acc0); acc1 = fmaf(xb1, wb1, acc1);
    acc0 = fmaf(xa2, wa2, acc0); acc1 = fmaf(xb2, wb2, acc1);
    acc0 = fmaf(xa3, wa3, acc0); acc1 = fmaf(xb3, wb3, acc1);
    j0 += 4; j1 += 4;
  }
  // row0 tail
  for (; j0 + 4 <= e0; j0 += 4) {
    int c0 = cols[j0], c1 = cols[j0 + 1], c2 = cols[j0 + 2], c3 = cols[j0 + 3];
    float x0 = b2f(xb[(long)c0 * 64 + f]);
    float x1 = b2f(xb[(long)c1 * 64 + f]);
    float x2 = b2f(xb[(long)c2 * 64 + f]);
    float x3 = b2f(xb[(long)c3 * 64 + f]);
    acc0 = fmaf(x0, dinv[c0], acc0);
    acc0 = fmaf(x1, dinv[c1], acc0);
    acc0 = fmaf(x2, dinv[c2], acc0);
    acc0 = fmaf(x3, dinv[c3], acc0);
  }
  for (; j0 < e0; ++j0) {
    int c = cols[j0];
    acc0 = fmaf(b2f(xb[(long)c * 64 + f]), dinv[c], acc0);
  }
  // row1 tail
  for (; j1 + 4 <= e1; j1 += 4) {
    int c0 = cols[j1], c1 = cols[j1 + 1], c2 = cols[j1 + 2], c3 = cols[j1 + 3];
    float x0 = b2f(xb[(long)c0 * 64 + f]);
    float x1 = b2f(xb[(long)c1 * 64 + f]);
    float x2 = b2f(xb[(long)c2 * 64 + f]);
    float x3 = b2f(xb[(long)c3 * 64 + f]);
    acc1 = fmaf(x0, dinv[c0], acc1);
    acc1 = fmaf(x1, dinv[c1], acc1);
    acc1 = fmaf(x2, dinv[c2], acc1);
    acc1 = fmaf(x3, dinv[c3], acc1);
  }
  for (; j1 < e1; ++j1) {
    int c = cols[j1];
    acc1 = fmaf(b2f(xb[(long)c * 64 + f]), dinv[c], acc1);
  }
  aggb[(long)r0 * 64 + f] = f2b(acc0 * d0);
  if (has1) aggb[(long)r1 * 64 + f] = f2b(acc1 * d1);
}

// ---------------------------------------------------------------------------
// One-shot weight prep:
//  blocks 0..63   : Wxpf = pack(W2x @ Wc_top)   (direct dot in packed order)
//  blocks 64..127 : Wapf = pack(W2a @ Wc_bot)
//  blocks 128..159: W1xf ; 160..191: W1af ; 192..223: Wclsf (simple packs)
//  block 224      : bp = b2x@Wc_top + b2a@Wc_bot + bc
// packed layout: dst[((nb*KB+kb)*64+l)*8+b] = W[kb*32+(l>>4)*8+b][nb*16+(l&15)]
// ---------------------------------------------------------------------------
__global__ __launch_bounds__(256) void k_wpack(
    const float* __restrict__ W1x, const float* __restrict__ W1a,
    const float* __restrict__ W2x, const float* __restrict__ W2a,
    const float* __restrict__ Wc, const float* __restrict__ b2x,
    const float* __restrict__ b2a, const float* __restrict__ bc,
    const float* __restrict__ Wcls,
    u16* __restrict__ W1xf, u16* __restrict__ W1af,
    u16* __restrict__ Wxpf, u16* __restrict__ Wapf,
    u16* __restrict__ Wclsf, float* __restrict__ bp) {
  const int blk = blockIdx.x, t = threadIdx.x;
  if (blk < 128) {
    const bool isX = blk < 64;
    int i = (isX ? blk : blk - 64) * 256 + t;        // packed index, K=128 Nc=128
    const float* W2 = isX ? W2x : W2a;
    const float* wc = isX ? Wc : Wc + 128 * 128;
    int b = i & 7, l = (i >> 3) & 63, fi = i >> 9;
    int kb = fi & 3, nb = fi >> 2;                   // KB = 4
    int k = kb * 32 + (l >> 4) * 8 + b;
    int n = nb * 16 + (l & 15);
    float s = 0.f;
    for (int m = 0; m < 128; ++m) s = fmaf(W2[k * 128 + m], wc[m * 128 + n], s);
    (isX ? Wxpf : Wapf)[i] = f2b(s);
  } else if (blk < 224) {
    const float* W; u16* dst; int K, Nc, i0;
    if (blk < 160)      { W = W1x;  dst = W1xf;  K = 64;  Nc = 128; i0 = blk - 128; }
    else if (blk < 192) { W = W1a;  dst = W1af;  K = 64;  Nc = 128; i0 = blk - 160; }
    else                { W = Wcls; dst = Wclsf; K = 128; Nc = 64;  i0 = blk - 192; }
    int i = i0 * 256 + t;
    if (i < K * Nc) {
      int b = i & 7, l = (i >> 3) & 63, fi = i >> 9;
      int KB = K >> 5;
      int kb = fi % KB, nb = fi / KB;
      int k = kb * 32 + (l >> 4) * 8 + b;
      int n = nb * 16 + (l & 15);
      dst[i] = f2b(W[k * Nc + n]);
    }
  } else if (t < 128) {
    float s = bc[t];
    for (int m = 0; m < 128; ++m)
      s += b2x[m] * Wc[m * 128 + t] + b2a[m] * Wc[(128 + m) * 128 + t];
    bp[t] = s;
  }
}

// ---------------------------------------------------------------------------
// Fused MLP (unchanged)
// ---------------------------------------------------------------------------
__global__ __launch_bounds__(256) void k_mlp(
    const u16* __restrict__ xb, const u16* __restrict__ aggb,
    const u16* __restrict__ W1xf, const u16* __restrict__ W1af,
    const float* __restrict__ b1x, const float* __restrict__ b1a,
    const u16* __restrict__ Wxpf, const u16* __restrict__ Wapf,
    const float* __restrict__ bp,
    const u16* __restrict__ Wclsf, const float* __restrict__ bcls,
    float* __restrict__ out, int N) {
  __shared__ u16 H1[4][16 * 256];   // 32KB
  __shared__ u16 H2[4][16 * 128];   // 16KB
  const int w = threadIdx.x >> 6;
  const int lane = threadIdx.x & 63;
  const int m0 = blockIdx.x * 64 + w * 16;
  const int lm = lane & 15;
  const int lq = lane >> 4;
  u16* h1 = H1[w];
  u16* h2 = H2[w];

  for (int br = 0; br < 2; ++br) {
    const u16* A = br ? aggb : xb;
    const u16* Wf = br ? W1af : W1xf;
    const float* bias = br ? b1a : b1x;
    const u16* ap = A + (long)(m0 + lm) * 64 + lq * 8;
    frag_ab a0 = *(const frag_ab*)(ap);
    frag_ab a1 = *(const frag_ab*)(ap + 32);
#pragma unroll
    for (int nb = 0; nb < 8; ++nb) {
      frag_ab b0 = *(const frag_ab*)(Wf + (size_t)((nb * 2 + 0) * 64 + lane) * 8);
      frag_ab b1v = *(const frag_ab*)(Wf + (size_t)((nb * 2 + 1) * 64 + lane) * 8);
      f32x4 acc = {0.f, 0.f, 0.f, 0.f};
      acc = __builtin_amdgcn_mfma_f32_16x16x32_bf16(a0, b0, acc, 0, 0, 0);
      acc = __builtin_amdgcn_mfma_f32_16x16x32_bf16(a1, b1v, acc, 0, 0, 0);
      int col = nb * 16 + lm;
      float bv = bias[col];
#pragma unroll
      for (int r = 0; r < 4; ++r) {
        int row = lq * 4 + r;
        h1[(row * 256 + br * 128 + col) ^ ((row & 7) << 3)] =
            f2b(fmaxf(acc[r] + bv, 0.f));
      }
    }
  }
  __syncthreads();

  frag_ab hfr[8];
#pragma unroll
  for (int kb = 0; kb < 8; ++kb)
    hfr[kb] = *(const frag_ab*)&h1[(lm * 256 + kb * 32 + lq * 8) ^ ((lm & 7) << 3)];
#pragma unroll
  for (int nb = 0; nb < 8; ++nb) {
    f32x4 acc = {0.f, 0.f, 0.f, 0.f};
#pragma unroll
    for (int kb = 0; kb < 8; ++kb) {
      const u16* Wf2 = (kb < 4) ? Wxpf : Wapf;
      frag_ab b = *(const frag_ab*)(Wf2 + (size_t)((nb * 4 + (kb & 3)) * 64 + lane) * 8);
      acc = __builtin_amdgcn_mfma_f32_16x16x32_bf16(hfr[kb], b, acc, 0, 0, 0);
    }
    int col = nb * 16 + lm;
    float bv = bp[col];
#pragma unroll
    for (int r = 0; r < 4; ++r) {
      int row = lq * 4 + r;
      h2[(row * 128 + col) ^ ((row & 7) << 3)] = f2b(fmaxf(acc[r] + bv, 0.f));
    }
  }
  __syncthreads();

  frag_ab h3[4];
#pragma unroll
  for (int kb = 0; kb < 4; ++kb)
    h3[kb] = *(const frag_ab*)&h2[(lm * 128 + kb * 32 + lq * 8) ^ ((lm & 7) << 3)];
#pragma unroll
  for (int nb = 0; nb < 4; ++nb) {
    f32x4 acc = {0.f, 0.f, 0.f, 0.f};
#pragma unroll
    for (int kb = 0; kb < 4; ++kb) {
      frag_ab b = *(const frag_ab*)(Wclsf + (size_t)((nb * 4 + kb) * 64 + lane) * 8);
      acc = __builtin_amdgcn_mfma_f32_16x16x32_bf16(h3[kb], b, acc, 0, 0, 0);
    }
    int col = nb * 16 + lm;
    float bv = bcls[col];
#pragma unroll
    for (int r = 0; r < 4; ++r) {
      int grow = m0 + lq * 4 + r;
      if (grow < N) out[(long)grow * 64 + col] = acc[r] + bv;
    }
  }
}

extern "C" void kernel_launch(void* const* d_in, const int* in_sizes, int n_in,
                              void* d_out, int out_size, void* d_ws, size_t ws_size,
                              hipStream_t stream) {
  const float* x    = (const float*)d_in[0];
  const void*  ei   = d_in[1];
  const float* W1x  = (const float*)d_in[2];
  const float* b1x  = (const float*)d_in[3];
  const float* W2x  = (const float*)d_in[4];
  const float* b2x  = (const float*)d_in[5];
  const float* W1a  = (const float*)d_in[6];
  const float* b1a  = (const float*)d_in[7];
  const float* W2a  = (const float*)d_in[8];
  const float* b2a  = (const float*)d_in[9];
  const float* Wc   = (const float*)d_in[10];
  const float* bc   = (const float*)d_in[11];
  const float* Wcls = (const float*)d_in[12];
  const float* bcls = (const float*)d_in[13];
  const int N = in_sizes[0] / 64;
  const int E = in_sizes[1] / 2;

  const int NB = (N + 511) >> 9;          // 512 rows per bucket
  const int NBpad = (NB + 63) & ~63;
  const int CH = (E + 255) / 256;

  float* ws = (float*)d_ws;
  long nAlign = (N + 255) & ~255L;
  float* dinv = ws;                                    // N
  int*   rowptr = (int*)(ws + nAlign);                 // N+1
  u16*   xb   = (u16*)(ws + 2 * nAlign + 256);         // N*64 bf16
  u16*   aggb = xb + (long)N * 64;                     // N*64 bf16
  float* bp   = (float*)(aggb + (long)N * 64);         // 128
  u16*   W1xf = (u16*)(bp + 128);                      // 8192
  u16*   W1af = W1xf + 8192;                           // 8192
  u16*   Wxpf = W1af + 8192;                           // 16384
  u16*   Wapf = Wxpf + 16384;                          // 16384
  u16*   Wclsf = Wapf + 16384;                         // 8192
  int*   bh   = (int*)(Wclsf + 8192);                  // 256*NBpad
  int*   bstart = bh + 256 * NBpad;                    // NB+1 (+pad)
  u32*   staged = (u32*)(bstart + NB + 64);            // E
  u32*   cols   = staged + E;                          // E
  float* out = (float*)d_out;

  k_bhist_cvt<<<256, 256, 0, stream>>>(ei, E, CH, NB, NBpad, bh, x, xb, (long)N * 64);
  k_cscan<<<1, 256, 0, stream>>>(bh, bstart, NB, NBpad, E);
  k_partition<<<256, 256, 0, stream>>>(ei, E, CH, NB, NBpad, bh, staged);
  k_csr_bucket<<<NB, 1024, 0, stream>>>(staged, bstart, rowptr, dinv, cols, N, E);
  k_aggregate<<<(N + 7) / 8, 256, 0, stream>>>(rowptr, cols, xb, dinv, aggb, N);
  k_wpack<<<225, 256, 0, stream>>>(W1x, W1a, W2x, W2a, Wc, b2x, b2a, bc, Wcls,
                                   W1xf, W1af, Wxpf, Wapf, Wclsf, bp);
  k_mlp<<<(N + 63) / 64, 256, 0, stream>>>(xb, aggb, W1xf, W1af, b1x, b1a,
                                           Wxpf, Wapf, bp, Wclsf, bcls, out, N);
}